// Round 13
// baseline (848.165 us; speedup 1.0000x reference)
//
#include <hip/hip_runtime.h>
#include <hip/hip_bf16.h>
#include <stdint.h>

#define NTOK 131072
#define NEXP 8
#define HPAD 132096   // NTOK + 1024 padded h rows per slot

typedef unsigned short ushortT;
typedef __attribute__((ext_vector_type(4))) float f32x4;
typedef __attribute__((ext_vector_type(8))) short s16x8;
typedef __attribute__((ext_vector_type(8))) __bf16 bf16x8;

__device__ __forceinline__ float bfu2f(unsigned short u){
  union { float f; uint32_t i; } c; c.i = ((uint32_t)u) << 16; return c.f;
}
__device__ __forceinline__ unsigned short f2bfu(float f){
  union { float f; uint32_t i; } c; c.f = f;
  uint32_t x = c.i;
  uint32_t r = (x + 0x7fffu + ((x >> 16) & 1u)) >> 16;  // RNE
  return (unsigned short)r;
}
// tanh-approx GELU (max abs err ~1e-3 vs erf form; threshold is 7e-2)
__device__ __forceinline__ float gelu_f(float x){
  float u = 0.7978845608028654f * (x + 0.044715f * x * x * x);
  float e = __expf(2.0f * u);
  float t = 1.0f - 2.0f / (e + 1.0f);
  return 0.5f * x * (1.0f + t);
}
__device__ __forceinline__ bf16x8 ldfrag(const void* p){
  s16x8 v = *(const s16x8*)p;
  return __builtin_bit_cast(bf16x8, v);
}

// async global->LDS, 16B per lane, wave-uniform LDS base + lane*16 (per-lane global src OK)
#define GLOAD16(g_, l_) \
  __builtin_amdgcn_global_load_lds((const __attribute__((address_space(1))) uint32_t*)(g_), \
                                   (__attribute__((address_space(3))) uint32_t*)(l_), 16, 0, 0)

// ---- zero the routing cursors ----
__global__ __launch_bounds__(64) void zero_cursors_kernel(int* __restrict__ cursors){
  if (threadIdx.x < 16) cursors[threadIdx.x] = 0;
}

// ---- pack W1 [E][D][H] / W2 [E][H][O] fp32 -> bf16 MFMA B-fragment order ----
// frag id fi = (e*32 + nb)*16 + s   (nb = n/16, s = k/32); 1KB per frag, lane-linear.
__global__ __launch_bounds__(256) void prep_w_kernel(const float* __restrict__ W1,
                                                     const float* __restrict__ W2,
                                                     ushortT* __restrict__ W1f,
                                                     ushortT* __restrict__ W2f){
  int bid = blockIdx.x;   // 1024 = 2 mats * 8 e * 8 ktile * 8 ntile
  const float* src; ushortT* dst;
  if (bid < 512){ src = W1; dst = W1f; } else { src = W2; dst = W2f; bid -= 512; }
  int e  = bid >> 6;
  int kt = (bid >> 3) & 7;
  int nt = bid & 7;
  __shared__ ushortT tileT[64][68];   // [n_local][k_local]
  int t = threadIdx.x;
  #pragma unroll
  for (int i = 0; i < 16; i++){
    int idx = t + i*256;
    int r = idx >> 6, c = idx & 63;   // r = k_local, c = n_local
    float v = src[((size_t)(e*512 + kt*64 + r))*512 + nt*64 + c];
    tileT[c][r] = f2bfu(v);
  }
  __syncthreads();
  int sub = t >> 6, l = t & 63;
  #pragma unroll
  for (int fo = 0; fo < 2; fo++){
    int fr  = sub + fo*4;             // local frag 0..7
    int nbl = fr >> 1;                // 0..3
    int ks  = fr & 1;
    int nb  = nt*4 + nbl;
    size_t fi = ((size_t)(e*32 + nb))*16 + kt*2 + ks;
    ushortT tmp[8];
    #pragma unroll
    for (int j = 0; j < 8; j++)
      tmp[j] = tileT[nbl*16 + (l & 15)][ks*32 + (l >> 4)*8 + j];
    *(s16x8*)(dst + fi*512 + l*8) = *(s16x8*)tmp;
  }
}

// ---- gating: logits(fp32) -> top2 -> weights; also emit x as bf16 ----
__global__ __launch_bounds__(256) void gating_kernel(const float* __restrict__ x,
                                                     const float* __restrict__ Wg,
                                                     ushortT* __restrict__ xbf,
                                                     int* __restrict__ epair,
                                                     float* __restrict__ wt){
  int l = threadIdx.x & 63;
  int wv = threadIdx.x >> 6;
  f32x4 wgv[16];
  #pragma unroll
  for (int i = 0; i < 8; i++){
    const f32x4* p = (const f32x4*)(Wg + (size_t)(l*8 + i)*8);
    wgv[2*i] = p[0]; wgv[2*i+1] = p[1];
  }
  int tbase = (blockIdx.x * 4 + wv) * 16;
  for (int tt = 0; tt < 16; tt++){
    int t = tbase + tt;
    const f32x4* xr = (const f32x4*)(x + (size_t)t*512 + l*8);
    f32x4 xa = xr[0], xb = xr[1];
    float acc[8];
    #pragma unroll
    for (int e2 = 0; e2 < 8; e2++) acc[e2] = 0.f;
    #pragma unroll
    for (int i = 0; i < 4; i++){
      float xi = xa[i], xj = xb[i];
      #pragma unroll
      for (int e2 = 0; e2 < 4; e2++){
        acc[e2]   += xi * wgv[2*i][e2];
        acc[4+e2] += xi * wgv[2*i+1][e2];
        acc[e2]   += xj * wgv[2*(i+4)][e2];
        acc[4+e2] += xj * wgv[2*(i+4)+1][e2];
      }
    }
    #pragma unroll
    for (int off = 1; off < 64; off <<= 1){
      #pragma unroll
      for (int e2 = 0; e2 < 8; e2++) acc[e2] += __shfl_xor(acc[e2], off);
    }
    int e0 = 0; float v0 = acc[0];
    #pragma unroll
    for (int e2 = 1; e2 < 8; e2++) if (acc[e2] > v0){ v0 = acc[e2]; e0 = e2; }
    int e1 = -1; float v1 = -3.4e38f;
    #pragma unroll
    for (int e2 = 0; e2 < 8; e2++){ if (e2 != e0 && acc[e2] > v1){ v1 = acc[e2]; e1 = e2; } }
    float w0 = 1.f / (1.f + __expf(v1 - v0));
    if (l == 0){
      epair[t] = e0 | (e1 << 4);
      wt[t] = w0;
      wt[NTOK + t] = 1.f - w0;
    }
    s16x8 o;
    #pragma unroll
    for (int j = 0; j < 4; j++){ o[j] = (short)f2bfu(xa[j]); o[4+j] = (short)f2bfu(xb[j]); }
    *(s16x8*)(xbf + (size_t)t*512 + l*8) = o;
  }
}

// ---- routing scatter ----
__global__ __launch_bounds__(256) void scatter_kernel(const int* __restrict__ epair,
                                                      int* __restrict__ cursors,
                                                      int* __restrict__ lists){
  __shared__ int cntL[16]; __shared__ int baseL[16];
  int tid = threadIdx.x;
  if (tid < 16) cntL[tid] = 0;
  __syncthreads();
  int t = blockIdx.x * 256 + tid;
  int p = epair[t];
  int e0 = p & 15, e1 = (p >> 4) & 15;
  int lp0 = atomicAdd(&cntL[e0], 1);
  int lp1 = atomicAdd(&cntL[8 + e1], 1);
  __syncthreads();
  if (tid < 16) baseL[tid] = atomicAdd(&cursors[tid], cntL[tid]);
  __syncthreads();
  lists[(size_t)e0 * NTOK + baseL[e0] + lp0] = t;
  lists[(size_t)(8 + e1) * NTOK + baseL[8 + e1] + lp1] = t;
}

// ================= G1: grouped gather-GEMM  h_raw = X[toks] @ W1[e] =========
// m97 2-phase: 128x128 tile, 4 waves (wave 64x64), BK=32, A+B staged via
// global_load_lds (4 per thread/step), double-buffered, 1 barrier/step.
// Epilogue: raw h (bf16) -> hraw; per-row partial (sum,sumsq) -> stats[row][8].
template<int SLOT>
__global__ __launch_bounds__(256, 3) void g1_kernel(
    const ushortT* __restrict__ xbf, const ushortT* __restrict__ W1bf,
    const int* __restrict__ cursors, const int* __restrict__ lists,
    ushortT* __restrict__ hraw, float* __restrict__ stats)
{
  __shared__ ushortT Abuf[2][4096];   // [128 rows][32k] linear, 8KB each
  __shared__ ushortT Bbuf[2][4096];   // 8 frags x 1KB each
  __shared__ int toksL[128];

  int tid = threadIdx.x, w = tid >> 6, l = tid & 63;
  int braw = (int)blockIdx.x;
  int bid = (braw & 7)*516 + (braw >> 3);     // XCD-chunked, 4128 = 8*516
  int t128 = bid >> 2, nt = bid & 3;

  int e = -1, tile = 0, bacc = 0, cn = 0;
  #pragma unroll
  for (int i = 0; i < 8; i++){
    int c = cursors[SLOT*8 + i];
    int ntl = (c + 127) >> 7;
    if (e < 0 && t128 < bacc + ntl){ e = i; tile = t128 - bacc; cn = c; }
    bacc += ntl;
  }
  if (e < 0) return;
  const int* lbase = lists + (size_t)(SLOT*8 + e) * NTOK;

  if (tid < 128){
    int idx = tile*128 + tid;
    toksL[tid] = lbase[(idx < cn) ? idx : tile*128];   // clamped (mask later)
  }
  __syncthreads();

  // per-thread stage sources (A: 2 rows' chunks; B: 2 frags), step strides 64B/1024B
  int rA0 = tid >> 2, rA1 = 64 + (tid >> 2), cA = tid & 3;
  int swzA = (cA ^ (rA0 & 3)) << 4;            // rA1&3 == rA0&3
  const char* srcA0 = (const char*)(xbf + (size_t)toksL[rA0]*512) + swzA;
  const char* srcA1 = (const char*)(xbf + (size_t)toksL[rA1]*512) + swzA;
  const char* srcB0 = (const char*)W1bf + ((size_t)((e*32 + nt*8 + w    )*16))*1024 + (l << 4);
  const char* srcB1 = (const char*)W1bf + ((size_t)((e*32 + nt*8 + w + 4)*16))*1024 + (l << 4);

#define STAGE_(b_, s_) { \
    GLOAD16(srcA0 + (size_t)(s_)*64,   &Abuf[b_][w*512]); \
    GLOAD16(srcA1 + (size_t)(s_)*64,   &Abuf[b_][2048 + w*512]); \
    GLOAD16(srcB0 + (size_t)(s_)*1024, &Bbuf[b_][w*512]); \
    GLOAD16(srcB1 + (size_t)(s_)*1024, &Bbuf[b_][2048 + w*512]); }

  int wr = w >> 1, wc = w & 1;
  int aswz = ((l >> 4) ^ (l & 3)) << 4;
  int ab0 = (wr*64 + (l & 15))*64 + aswz;      // + m*16*64
  int bb0 = (wc*4)*1024 + (l << 4);            // + nf*1024

  f32x4 acc[4][4];
  #pragma unroll
  for (int m = 0; m < 4; m++)
    #pragma unroll
    for (int nf = 0; nf < 4; nf++) acc[m][nf] = (f32x4){0.f,0.f,0.f,0.f};

  STAGE_(0, 0);
  __syncthreads();
  for (int s = 0; s < 16; s++){
    int b = s & 1;
    if (s < 15) STAGE_(b ^ 1, s + 1);
    bf16x8 A[4], B[4];
    #pragma unroll
    for (int m = 0; m < 4; m++)  A[m]  = ldfrag((const char*)&Abuf[b][0] + ab0 + m*1024);
    #pragma unroll
    for (int nf = 0; nf < 4; nf++) B[nf] = ldfrag((const char*)&Bbuf[b][0] + bb0 + nf*1024);
    #pragma unroll
    for (int nf = 0; nf < 4; nf++)
      #pragma unroll
      for (int m = 0; m < 4; m++)
        acc[m][nf] = __builtin_amdgcn_mfma_f32_16x16x32_bf16(A[m], B[nf], acc[m][nf], 0, 0, 0);
    __syncthreads();
  }
#undef STAGE_

  // epilogue: raw h + per-row 64-col partials (non-atomic, slot nt*2+wc of 8)
  #pragma unroll
  for (int m = 0; m < 4; m++){
    #pragma unroll
    for (int j = 0; j < 4; j++){
      float s1 = acc[m][0][j] + acc[m][1][j] + acc[m][2][j] + acc[m][3][j];
      float q1 = acc[m][0][j]*acc[m][0][j] + acc[m][1][j]*acc[m][1][j]
               + acc[m][2][j]*acc[m][2][j] + acc[m][3][j]*acc[m][3][j];
      s1 += __shfl_xor(s1, 1); q1 += __shfl_xor(q1, 1);
      s1 += __shfl_xor(s1, 2); q1 += __shfl_xor(q1, 2);
      s1 += __shfl_xor(s1, 4); q1 += __shfl_xor(q1, 4);
      s1 += __shfl_xor(s1, 8); q1 += __shfl_xor(q1, 8);
      int r = wr*64 + m*16 + (l >> 4)*4 + j;
      int i = tile*128 + r;
      if (i < cn){
        size_t grow = (size_t)t128*128 + r;
        if ((l & 15) == 0){
          float2 v; v.x = s1; v.y = q1;
          *((float2*)stats + grow*8 + (nt*2 + wc)) = v;
        }
        #pragma unroll
        for (int nf = 0; nf < 4; nf++)
          hraw[grow*512 + nt*128 + wc*64 + nf*16 + (l & 15)] = f2bfu(acc[m][nf][j]);
      }
    }
  }
}

// ================= LNG: in-place LN + GELU over hraw =================
template<int SLOT>
__global__ __launch_bounds__(256) void lng_kernel(
    const int* __restrict__ cursors, const float* __restrict__ stats,
    const float* __restrict__ gamma, const float* __restrict__ beta,
    ushortT* __restrict__ hraw)
{
  __shared__ float gL[512], bL[512], muL[64], rsL[64];
  int tid = threadIdx.x;
  int braw = (int)blockIdx.x;
  int t64 = (braw & 7)*258 + (braw >> 3);     // 2064 = 8*258
  int e = -1, bacc = 0, tstart = 0, cn = 0;
  #pragma unroll
  for (int i = 0; i < 8; i++){
    int c = cursors[SLOT*8 + i];
    int ntl = 2*((c + 127) >> 7);
    if (e < 0 && t64 < bacc + ntl){ e = i; tstart = bacc; cn = c; }
    bacc += ntl;
  }
  if (e < 0) return;
  gL[tid] = gamma[e*512 + tid]; gL[tid+256] = gamma[e*512 + 256 + tid];
  bL[tid] = beta [e*512 + tid]; bL[tid+256] = beta [e*512 + 256 + tid];
  if (tid < 64){
    size_t grow = (size_t)t64*64 + tid;
    const float2* sp = (const float2*)stats + grow*8;
    float s = 0.f, q = 0.f;
    #pragma unroll
    for (int k = 0; k < 8; k++){ float2 v = sp[k]; s += v.x; q += v.y; }
    float mu = s * (1.f/512.f);
    float var = q * (1.f/512.f) - mu*mu;
    muL[tid] = mu;
    rsL[tid] = rsqrtf(var + 1e-5f);
  }
  __syncthreads();
  int lrow0 = (t64 - tstart)*64;
  for (int v = tid; v < 4096; v += 256){
    int r = v >> 6, cv = v & 63;
    size_t grow = (size_t)t64*64 + r;
    ushortT* p = hraw + grow*512 + cv*8;
    s16x8 o;
    if (lrow0 + r < cn){
      s16x8 u = *(s16x8*)p;
      float mu = muL[r], rs = rsL[r];
      #pragma unroll
      for (int j = 0; j < 8; j++){
        int col = cv*8 + j;
        float val = (bfu2f((unsigned short)u[j]) - mu)*rs*gL[col] + bL[col];
        o[j] = (short)f2bfu(gelu_f(val));
      }
    } else {
      #pragma unroll
      for (int j = 0; j < 8; j++) o[j] = 0;   // keep padded rows bounded/deterministic
    }
    *(s16x8*)p = o;
  }
}

// ================= G2: grouped GEMM  out[tok] (+)= w * (h' @ W2[e]) =========
template<int SLOT>
__global__ __launch_bounds__(256, 3) void g2_kernel(
    const ushortT* __restrict__ hraw, const ushortT* __restrict__ W2bf,
    const float* __restrict__ wt, const int* __restrict__ cursors,
    const int* __restrict__ lists, float* __restrict__ out)
{
  __shared__ ushortT Abuf[2][4096];
  __shared__ ushortT Bbuf[2][4096];
  __shared__ int   toksL[128];
  __shared__ float wrowL[128];

  int tid = threadIdx.x, w = tid >> 6, l = tid & 63;
  int braw = (int)blockIdx.x;
  int bid = (braw & 7)*516 + (braw >> 3);
  int t128 = bid >> 2, nt = bid & 3;

  int e = -1, tile = 0, bacc = 0, cn = 0;
  #pragma unroll
  for (int i = 0; i < 8; i++){
    int c = cursors[SLOT*8 + i];
    int ntl = (c + 127) >> 7;
    if (e < 0 && t128 < bacc + ntl){ e = i; tile = t128 - bacc; cn = c; }
    bacc += ntl;
  }
  if (e < 0) return;
  const int* lbase = lists + (size_t)(SLOT*8 + e) * NTOK;

  if (tid < 128){
    int idx = tile*128 + tid;
    int tok = lbase[(idx < cn) ? idx : tile*128];
    toksL[tid] = tok;
    wrowL[tid] = wt[(size_t)SLOT*NTOK + tok];
  }

  int rA0 = tid >> 2, rA1 = 64 + (tid >> 2), cA = tid & 3;
  int swzA = (cA ^ (rA0 & 3)) << 4;
  const char* srcA0 = (const char*)(hraw + ((size_t)t128*128 + rA0)*512) + swzA;
  const char* srcA1 = (const char*)(hraw + ((size_t)t128*128 + rA1)*512) + swzA;
  const char* srcB0 = (const char*)W2bf + ((size_t)((e*32 + nt*8 + w    )*16))*1024 + (l << 4);
  const char* srcB1 = (const char*)W2bf + ((size_t)((e*32 + nt*8 + w + 4)*16))*1024 + (l << 4);

#define STAGE_(b_, s_) { \
    GLOAD16(srcA0 + (size_t)(s_)*64,   &Abuf[b_][w*512]); \
    GLOAD16(srcA1 + (size_t)(s_)*64,   &Abuf[b_][2048 + w*512]); \
    GLOAD16(srcB0 + (size_t)(s_)*1024, &Bbuf[b_][w*512]); \
    GLOAD16(srcB1 + (size_t)(s_)*1024, &Bbuf[b_][2048 + w*512]); }

  int wr = w >> 1, wc = w & 1;
  int aswz = ((l >> 4) ^ (l & 3)) << 4;
  int ab0 = (wr*64 + (l & 15))*64 + aswz;
  int bb0 = (wc*4)*1024 + (l << 4);

  f32x4 acc[4][4];
  #pragma unroll
  for (int m = 0; m < 4; m++)
    #pragma unroll
    for (int nf = 0; nf < 4; nf++) acc[m][nf] = (f32x4){0.f,0.f,0.f,0.f};

  STAGE_(0, 0);
  __syncthreads();
  for (int s = 0; s < 16; s++){
    int b = s & 1;
    if (s < 15) STAGE_(b ^ 1, s + 1);
    bf16x8 A[4], B[4];
    #pragma unroll
    for (int m = 0; m < 4; m++)  A[m]  = ldfrag((const char*)&Abuf[b][0] + ab0 + m*1024);
    #pragma unroll
    for (int nf = 0; nf < 4; nf++) B[nf] = ldfrag((const char*)&Bbuf[b][0] + bb0 + nf*1024);
    #pragma unroll
    for (int nf = 0; nf < 4; nf++)
      #pragma unroll
      for (int m = 0; m < 4; m++)
        acc[m][nf] = __builtin_amdgcn_mfma_f32_16x16x32_bf16(A[m], B[nf], acc[m][nf], 0, 0, 0);
    __syncthreads();
  }
#undef STAGE_

  #pragma unroll
  for (int m = 0; m < 4; m++){
    #pragma unroll
    for (int j = 0; j < 4; j++){
      int r = wr*64 + m*16 + (l >> 4)*4 + j;
      int i = tile*128 + r;
      if (i < cn){
        int tok = toksL[r];
        float wr_ = wrowL[r];
        #pragma unroll
        for (int nf = 0; nf < 4; nf++){
          int col = nt*128 + wc*64 + nf*16 + (l & 15);
          float val = acc[m][nf][j] * wr_;
          float* p = out + (size_t)tok*512 + col;
          if (SLOT == 0) *p = val; else *p += val;
        }
      }
    }
  }
}

extern "C" void kernel_launch(void* const* d_in, const int* in_sizes, int n_in,
                              void* d_out, int out_size, void* d_ws, size_t ws_size,
                              hipStream_t stream){
  const float* x     = (const float*)d_in[0];
  const float* Wg    = (const float*)d_in[1];
  const float* W1    = (const float*)d_in[2];
  const float* gamma = (const float*)d_in[3];
  const float* beta  = (const float*)d_in[4];
  const float* W2    = (const float*)d_in[5];
  float* out = (float*)d_out;

  char* ws = (char*)d_ws;
  size_t off = 0;
  ushortT* xbf   = (ushortT*)(ws + off); off += (size_t)NTOK*512*2;        // 134.2 MB
  ushortT* W1bf  = (ushortT*)(ws + off); off += (size_t)8*512*512*2;       // 4.2 MB
  ushortT* W2bf  = (ushortT*)(ws + off); off += (size_t)8*512*512*2;       // 4.2 MB
  int*     lists = (int*)(ws + off);     off += (size_t)16*NTOK*4;         // 8.4 MB
  float*   wtp   = (float*)(ws + off);   off += (size_t)2*NTOK*4;          // 1.0 MB
  int*     epair = (int*)(ws + off);     off += (size_t)NTOK*4;            // 0.5 MB
  int*     cursors = (int*)(ws + off);   off += 256;
  float*   stats = (float*)(ws + off);   off += (size_t)HPAD*8*2*4;        // 8.5 MB
  ushortT* hraw  = (ushortT*)(ws + off); off += (size_t)HPAD*512*2;        // 135.3 MB

  zero_cursors_kernel<<<1, 64, 0, stream>>>(cursors);
  prep_w_kernel<<<1024, 256, 0, stream>>>(W1, W2, W1bf, W2bf);
  gating_kernel<<<NTOK/64, 256, 0, stream>>>(x, Wg, xbf, epair, wtp);
  scatter_kernel<<<NTOK/256, 256, 0, stream>>>(epair, cursors, lists);

  g1_kernel<0><<<4128, 256, 0, stream>>>(xbf, W1bf, cursors, lists, hraw, stats);
  lng_kernel<0><<<2064, 256, 0, stream>>>(cursors, stats, gamma, beta, hraw);
  g2_kernel<0><<<4128, 256, 0, stream>>>(hraw, W2bf, wtp, cursors, lists, out);

  g1_kernel<1><<<4128, 256, 0, stream>>>(xbf, W1bf, cursors, lists, hraw, stats);
  lng_kernel<1><<<2064, 256, 0, stream>>>(cursors, stats, gamma, beta, hraw);
  g2_kernel<1><<<4128, 256, 0, stream>>>(hraw, W2bf, wtp, cursors, lists, out);
}